// Round 1
// baseline (9297.768 us; speedup 1.0000x reference)
//
#include <hip/hip_runtime.h>
#include <math.h>

// Problem constants
constexpr int B  = 64;
constexpr int T  = 31;
constexpr int S  = 32;
constexpr int V  = 34004;
constexpr int E  = 300;
constexpr int H  = 512;
constexpr int M  = 1024;
constexpr int FH = 2048;  // 4*H

// ---------------------------------------------------------------------------
// init: h = h0, c = c0, attn = 0
__global__ __launch_bounds__(256) void k_init(const float* __restrict__ h0,
                                              const float* __restrict__ c0,
                                              float* __restrict__ h,
                                              float* __restrict__ c,
                                              float* __restrict__ attn) {
    int i = blockIdx.x * 256 + threadIdx.x;
    if (i < B * H) { h[i] = h0[i]; c[i] = c0[i]; attn[i] = 0.f; }
}

// ---------------------------------------------------------------------------
// xk[t*B+b][col] = bias[col] + sum_e emb[tok(b,t)][e] * Wk[e][col]
// grid (124, 8), block 256.  16 rows x 256 cols per block.
__global__ __launch_bounds__(256) void k_xk(const int* __restrict__ dec,
                                            const float* __restrict__ emb,
                                            const float* __restrict__ Wk,
                                            const float* __restrict__ bias,
                                            float* __restrict__ xk) {
    __shared__ float Als[16][E];
    __shared__ int toks[16];
    int rowbase = blockIdx.x * 16;
    int col = blockIdx.y * 256 + threadIdx.x;
    if (threadIdx.x < 16) {
        int row = rowbase + threadIdx.x;     // row = t*B + b
        int t = row / B, b = row % B;
        toks[threadIdx.x] = dec[b * T + t];
    }
    __syncthreads();
    for (int i = threadIdx.x; i < 16 * E; i += 256) {
        int r = i / E, e = i % E;
        Als[r][e] = emb[(long)toks[r] * E + e];
    }
    __syncthreads();
    float acc[16];
#pragma unroll
    for (int r = 0; r < 16; ++r) acc[r] = 0.f;
    for (int e = 0; e < E; ++e) {
        float w = Wk[(long)e * FH + col];
#pragma unroll
        for (int r = 0; r < 16; ++r) acc[r] += Als[r][e] * w;
    }
    float bb = bias[col];
#pragma unroll
    for (int r = 0; r < 16; ++r)
        xk[(long)(rowbase + r) * FH + col] = acc[r] + bb;
}

// ---------------------------------------------------------------------------
// keys[b*S+s][col] = sum_m memory[b][s][m] * Wm[m][col]
// grid (128, 2), block 256.  16 rows x 256 cols, K chunked by 256.
__global__ __launch_bounds__(256) void k_keys(const float* __restrict__ memory,
                                              const float* __restrict__ Wm,
                                              float* __restrict__ keys) {
    __shared__ float Als[16][256];
    int rowbase = blockIdx.x * 16;
    int col = blockIdx.y * 256 + threadIdx.x;
    float acc[16];
#pragma unroll
    for (int r = 0; r < 16; ++r) acc[r] = 0.f;
    for (int kc = 0; kc < M; kc += 256) {
        __syncthreads();
        for (int i = threadIdx.x; i < 16 * 256; i += 256) {
            int r = i / 256, k = i % 256;
            Als[r][k] = memory[(long)(rowbase + r) * M + kc + k];
        }
        __syncthreads();
        for (int k = 0; k < 256; ++k) {
            float w = Wm[(long)(kc + k) * H + col];
#pragma unroll
            for (int r = 0; r < 16; ++r) acc[r] += Als[r][k] * w;
        }
    }
#pragma unroll
    for (int r = 0; r < 16; ++r)
        keys[(long)(rowbase + r) * H + col] = acc[r];
}

// ---------------------------------------------------------------------------
// Step kernel 1: z = xk_t + [attn, h_in] @ [Wk[300:]; Wr]  (bias already in xk)
// then LSTM: c2 = sig(f)*c + sig(i)*tanh(g); h2 = sig(o)*tanh(c2)
// grid (8 row-tiles of 8, 8 j-tiles of 64), block 256 = 64 j x 4 gates.
__global__ __launch_bounds__(256) void k_step1(const float* __restrict__ xk_t,
                                               const float* __restrict__ attn,
                                               const float* __restrict__ h_in,
                                               const float* __restrict__ Wk,
                                               const float* __restrict__ Wr,
                                               float* __restrict__ c,
                                               float* __restrict__ h_out) {
    __shared__ float Als[8][256];
    __shared__ float Zls[8][4][64];
    int rb = blockIdx.x * 8;
    int jj = threadIdx.x % 64;
    int gate = threadIdx.x / 64;
    int jcol = blockIdx.y * 64 + jj;
    int col = jcol + gate * H;
    float acc[8];
#pragma unroll
    for (int r = 0; r < 8; ++r) acc[r] = 0.f;
    for (int kc = 0; kc < 1024; kc += 256) {
        __syncthreads();
        for (int i = threadIdx.x; i < 8 * 256; i += 256) {
            int r = i / 256, k = i % 256;
            int kk = kc + k;
            Als[r][k] = (kk < H) ? attn[(rb + r) * H + kk]
                                 : h_in[(rb + r) * H + kk - H];
        }
        __syncthreads();
        if (kc < H) {  // uniform per chunk: kc in {0,256} -> Wk part
            for (int k = 0; k < 256; ++k) {
                float w = Wk[(long)(E + kc + k) * FH + col];
#pragma unroll
                for (int r = 0; r < 8; ++r) acc[r] += Als[r][k] * w;
            }
        } else {       // kc in {512,768} -> Wr part
            for (int k = 0; k < 256; ++k) {
                float w = Wr[(long)(kc - H + k) * FH + col];
#pragma unroll
                for (int r = 0; r < 8; ++r) acc[r] += Als[r][k] * w;
            }
        }
    }
#pragma unroll
    for (int r = 0; r < 8; ++r)
        Zls[r][gate][jj] = acc[r] + xk_t[(rb + r) * FH + col];
    __syncthreads();
    for (int idx = threadIdx.x; idx < 8 * 64; idx += 256) {
        int r = idx / 64, j2 = idx % 64;
        float zi = Zls[r][0][j2], zf = Zls[r][1][j2];
        float zg = Zls[r][2][j2], zo = Zls[r][3][j2];
        int b = rb + r;
        int j = blockIdx.y * 64 + j2;
        float cold = c[b * H + j];
        float ig = 1.f / (1.f + __expf(-zi));
        float fg = 1.f / (1.f + __expf(-zf));
        float og = 1.f / (1.f + __expf(-zo));
        float c2 = fg * cold + ig * tanhf(zg);
        float h2 = og * tanhf(c2);
        c[b * H + j] = c2;
        h_out[b * H + j] = h2;
    }
}

// ---------------------------------------------------------------------------
// Step kernel 2: q = h2 @ Wq; score_s = v . tanh(keys[b,s,:] + q);
// al = softmax(score); ctx = sum_s al_s * memory[b,s,:]
// grid 64 (one block per b), block 256.
__global__ __launch_bounds__(256) void k_step2(const float* __restrict__ h2,
                                               const float* __restrict__ keys,
                                               const float* __restrict__ memory,
                                               const float* __restrict__ Wq,
                                               const float* __restrict__ vvec,
                                               float* __restrict__ ctx) {
    __shared__ float hrow[H];
    __shared__ float qrow[H];
    __shared__ float red[S][8];
    __shared__ float al[S];
    int b = blockIdx.x;
    for (int i = threadIdx.x; i < H; i += 256) hrow[i] = h2[b * H + i];
    __syncthreads();
    // q: each thread 2 columns
    {
        int c0 = threadIdx.x, c1 = threadIdx.x + 256;
        float a0 = 0.f, a1 = 0.f;
        for (int k = 0; k < H; ++k) {
            float hv = hrow[k];
            a0 += hv * Wq[(long)k * H + c0];
            a1 += hv * Wq[(long)k * H + c1];
        }
        qrow[c0] = a0; qrow[c1] = a1;
    }
    __syncthreads();
    // scores: 8 threads per s
    {
        int s = threadIdx.x / 8, part = threadIdx.x % 8;
        float sc = 0.f;
        for (int hh = part; hh < H; hh += 8)
            sc += vvec[hh] * tanhf(keys[(long)(b * S + s) * H + hh] + qrow[hh]);
        red[s][part] = sc;
    }
    __syncthreads();
    if (threadIdx.x < S) {
        float t = 0.f;
        for (int p = 0; p < 8; ++p) t += red[threadIdx.x][p];
        red[threadIdx.x][0] = t;
    }
    __syncthreads();
    if (threadIdx.x == 0) {
        float mx = -1e30f;
        for (int ss = 0; ss < S; ++ss) mx = fmaxf(mx, red[ss][0]);
        float sum = 0.f;
        for (int ss = 0; ss < S; ++ss) {
            float e = __expf(red[ss][0] - mx);
            al[ss] = e; sum += e;
        }
        float inv = 1.f / sum;
        for (int ss = 0; ss < S; ++ss) al[ss] *= inv;
    }
    __syncthreads();
    for (int m = threadIdx.x; m < M; m += 256) {
        float acc = 0.f;
#pragma unroll
        for (int ss = 0; ss < S; ++ss)
            acc += al[ss] * memory[((long)b * S + ss) * M + m];
        ctx[b * M + m] = acc;
    }
}

// ---------------------------------------------------------------------------
// Step kernel 3: attn2 = [h2, ctx] @ Wa  -> feeds back as attn, stored to a2_t
// grid (16 row-tiles of 4, 2 col-tiles of 256), block 256.
__global__ __launch_bounds__(256) void k_step3(const float* __restrict__ h2,
                                               const float* __restrict__ ctx,
                                               const float* __restrict__ Wa,
                                               float* __restrict__ attn,
                                               float* __restrict__ a2_t) {
    __shared__ float Als[4][256];
    int rb = blockIdx.x * 4;
    int col = blockIdx.y * 256 + threadIdx.x;
    float acc[4] = {0.f, 0.f, 0.f, 0.f};
    for (int kc = 0; kc < H + M; kc += 256) {
        __syncthreads();
        for (int i = threadIdx.x; i < 4 * 256; i += 256) {
            int r = i / 256, k = i % 256;
            int kk = kc + k;
            Als[r][k] = (kk < H) ? h2[(rb + r) * H + kk]
                                 : ctx[(rb + r) * M + kk - H];
        }
        __syncthreads();
        for (int k = 0; k < 256; ++k) {
            float w = Wa[(long)(kc + k) * H + col];
#pragma unroll
            for (int r = 0; r < 4; ++r) acc[r] += Als[r][k] * w;
        }
    }
#pragma unroll
    for (int r = 0; r < 4; ++r) {
        float v2 = acc[r];
        attn[(rb + r) * H + col] = v2;
        a2_t[(rb + r) * H + col] = v2;
    }
}

// ---------------------------------------------------------------------------
// logits: out[b][t][col] = a2[t*B+b] . Wfc[:,col] + bfc[col]
// 128x128 block tile, 8x8 per thread, BK=16.  grid (16, 266), block 256.
constexpr int BM = 128, BN = 128, BK = 16;
__global__ __launch_bounds__(256) void k_logits(const float* __restrict__ A,
                                                const float* __restrict__ Wfc,
                                                const float* __restrict__ bfc,
                                                float* __restrict__ out) {
    __shared__ float As[BK][BM + 1];
    __shared__ float Bs[BK][BN];
    int bm = blockIdx.x * BM;
    int bn = blockIdx.y * BN;
    int tid = threadIdx.x;
    int tx = tid % 16, ty = tid / 16;
    float acc[8][8];
#pragma unroll
    for (int i = 0; i < 8; ++i)
#pragma unroll
        for (int j = 0; j < 8; ++j) acc[i][j] = 0.f;

    for (int kc = 0; kc < H; kc += BK) {
        for (int i = tid; i < BM * BK; i += 256) {
            int m = i / BK, k = i % BK;
            int ra = bm + m;
            As[k][m] = (ra < T * B) ? A[(long)ra * H + kc + k] : 0.f;
        }
        for (int i = tid; i < BK * BN; i += 256) {
            int k = i / BN, n = i % BN;
            int cn = bn + n;
            Bs[k][n] = (cn < V) ? Wfc[(long)(kc + k) * V + cn] : 0.f;
        }
        __syncthreads();
#pragma unroll
        for (int k = 0; k < BK; ++k) {
            float ar[8], br[8];
#pragma unroll
            for (int i = 0; i < 8; ++i) ar[i] = As[k][ty * 8 + i];
#pragma unroll
            for (int j = 0; j < 8; ++j) br[j] = Bs[k][tx * 8 + j];
#pragma unroll
            for (int i = 0; i < 8; ++i)
#pragma unroll
                for (int j = 0; j < 8; ++j) acc[i][j] += ar[i] * br[j];
        }
        __syncthreads();
    }
#pragma unroll
    for (int i = 0; i < 8; ++i) {
        int ra = bm + ty * 8 + i;
        if (ra >= T * B) continue;
        int t = ra >> 6;        // ra = t*B + b, B = 64
        int b = ra & 63;
        long ro = (long)(b * T + t) * V;
#pragma unroll
        for (int j = 0; j < 8; ++j) {
            int cn = bn + tx * 8 + j;
            if (cn < V) out[ro + cn] = acc[i][j] + bfc[cn];
        }
    }
}

// ---------------------------------------------------------------------------
extern "C" void kernel_launch(void* const* d_in, const int* in_sizes, int n_in,
                              void* d_out, int out_size, void* d_ws, size_t ws_size,
                              hipStream_t stream) {
    const int*   dec    = (const int*)d_in[0];
    const float* memory = (const float*)d_in[1];
    const float* h0     = (const float*)d_in[2];
    const float* c0     = (const float*)d_in[3];
    const float* emb    = (const float*)d_in[4];
    const float* Wk     = (const float*)d_in[5];
    const float* Wr     = (const float*)d_in[6];
    const float* bvec   = (const float*)d_in[7];
    const float* Wm     = (const float*)d_in[8];
    const float* Wq     = (const float*)d_in[9];
    const float* vvec   = (const float*)d_in[10];
    const float* Wa     = (const float*)d_in[11];
    const float* Wfc    = (const float*)d_in[12];
    const float* bfc    = (const float*)d_in[13];
    float* out = (float*)d_out;

    float* ws   = (float*)d_ws;
    float* xk   = ws;                       // [T*B][FH]
    float* keys = xk + (size_t)T * B * FH;  // [B*S][H]
    float* hA   = keys + (size_t)B * S * H; // [B][H]
    float* hB   = hA + B * H;
    float* cbuf = hB + B * H;
    float* attn = cbuf + B * H;
    float* ctx  = attn + B * H;             // [B][M]
    float* a2   = ctx + (size_t)B * M;      // [T*B][H]

    k_init<<<dim3((B * H + 255) / 256), 256, 0, stream>>>(h0, c0, hA, cbuf, attn);
    k_xk<<<dim3((T * B) / 16, FH / 256), 256, 0, stream>>>(dec, emb, Wk, bvec, xk);
    k_keys<<<dim3((B * S) / 16, H / 256), 256, 0, stream>>>(memory, Wm, keys);

    for (int t = 0; t < T; ++t) {
        const float* hin = (t & 1) ? hB : hA;
        float* hout      = (t & 1) ? hA : hB;
        k_step1<<<dim3(8, 8), 256, 0, stream>>>(xk + (size_t)t * B * FH, attn,
                                                hin, Wk, Wr, cbuf, hout);
        k_step2<<<dim3(64), 256, 0, stream>>>(hout, keys, memory, Wq, vvec, ctx);
        k_step3<<<dim3(16, 2), 256, 0, stream>>>(hout, ctx, Wa, attn,
                                                 a2 + (size_t)t * B * H);
    }

    k_logits<<<dim3(16, 266), 256, 0, stream>>>(a2, Wfc, bfc, out);
}